// Round 8
// baseline (1476.639 us; speedup 1.0000x reference)
//
#include <hip/hip_runtime.h>

// NGCF forward on gfx950 — round 14: slice-phased SpMM passes.
// R13 post-mortem: fetch granule = 128 B (int8 gather portion 325 MB > 307 MB
// zero-hit bound) -> bf16@3.9 and int8@4.1 TB/s both saturate the same
// ~4 TB/s memory-side granule ceiling. Only lever left: make gathers HIT L2.
// R12's per-row bucket order failed (2-edge phases, no lockstep); enforce
// temporal confinement with SEPARATE KERNEL PASSES: cols split into 3 slices
// of 50K nodes (3.2 MB cur8, fits 4 MB XCD L2). place_edges slice-sorts each
// row and emits 2 extra sub-pointers/row. Pass 0 writes nbuf, passes 1-2 RMW
// it (coalesced). Every gather in a pass targets one resident slice.

#define EMB 64

constexpr int kNUsers = 100000;
constexpr int kNItems = 50000;
constexpr int kNNodes = 150000;
constexpr int kNEdges = 4800000;
constexpr int kBatch  = 16384;
constexpr int kLayers = 3;
constexpr int kRngShift = 8;                     // 256 rows per range
constexpr int kNRanges  = (kNNodes + 255) >> 8;  // 586
constexpr int kEdgesPerBin = 16384;              // edges per bin block
constexpr int kBinBlocks = (kNEdges + kEdgesPerBin - 1) / kEdgesPerBin; // 293
constexpr int kSlice1 = 50000;                   // col-slice boundaries
constexpr int kSlice2 = 100000;
constexpr int kEPW    = 16;                      // fallback only

__device__ __forceinline__ float f4c(const float4& v, int i) {
  return ((const float*)&v)[i];
}
__device__ __forceinline__ float4 f4fma(float s, float4 w, float4 a) {
  a.x = fmaf(s, w.x, a.x);
  a.y = fmaf(s, w.y, a.y);
  a.z = fmaf(s, w.z, a.z);
  a.w = fmaf(s, w.w, a.w);
  return a;
}
__device__ __forceinline__ float4 f4add(float4 a, float4 b) {
  a.x += b.x; a.y += b.y; a.z += b.z; a.w += b.w;
  return a;
}
__device__ __forceinline__ float lrelu(float x) { return x > 0.f ? x : 0.2f * x; }

#define F16(M) M(0) M(1) M(2) M(3) M(4) M(5) M(6) M(7) \
               M(8) M(9) M(10) M(11) M(12) M(13) M(14) M(15)

// ---------------------------------------------------------------------------
// init: cur = concat(user_emb, item_emb).
// ---------------------------------------------------------------------------
__global__ __launch_bounds__(256) void init_embed(
    const float* __restrict__ user_emb, const float* __restrict__ item_emb,
    float* __restrict__ cur)
{
  const size_t userF = (size_t)kNUsers * EMB;
  const size_t allF4 = (size_t)kNNodes * EMB / 4;
  const size_t i = (size_t)blockIdx.x * 256 + threadIdx.x;
  if (i >= allF4) return;
  const size_t f = i * 4;
  const float4 v = (f < userF) ? ((const float4*)user_emb)[i]
                               : ((const float4*)(item_emb))[(f - userF) / 4];
  ((float4*)cur)[i] = v;
}

// int8 shadow refresh: per-row-max symmetric quant. One wave per row.
__global__ __launch_bounds__(256) void quant8(
    const float* __restrict__ cur, signed char* __restrict__ cur8,
    float* __restrict__ rowScale)
{
  const int lane = threadIdx.x & 63;
  const int r = (blockIdx.x << 2) | (threadIdx.x >> 6);
  if (r >= kNNodes) return;
  const float v = cur[(size_t)r * EMB + lane];
  float m = fabsf(v);
#pragma unroll
  for (int off = 32; off >= 1; off >>= 1)
    m = fmaxf(m, __shfl_xor(m, off, 64));
  const float inv = (m > 0.f) ? (127.0f / m) : 0.f;
  cur8[(size_t)r * EMB + lane] = (signed char)__float2int_rn(v * inv);
  if (lane == 0) rowScale[r] = m * (1.0f / 127.0f);
}

// ---------------------------------------------------------------------------
// CSR build: range histogram -> range scan -> burst binning -> local place.
// ---------------------------------------------------------------------------

// Per-block LDS histogram over 586 ranges; one global atomic per (block,range).
__global__ __launch_bounds__(1024) void hist_ranges(
    const int* __restrict__ rows, int* __restrict__ rangeA)
{
  __shared__ int cnt[kNRanges];
  const int tid = threadIdx.x;
  const int e0  = blockIdx.x * kEdgesPerBin;
  int e1 = e0 + kEdgesPerBin;
  if (e1 > kNEdges) e1 = kNEdges;
  for (int b = tid; b < kNRanges; b += 1024) cnt[b] = 0;
  __syncthreads();
  for (int e = e0 + tid; e < e1; e += 1024)
    atomicAdd(&cnt[rows[e] >> kRngShift], 1);
  __syncthreads();
  for (int b = tid; b < kNRanges; b += 1024)
    if (cnt[b] > 0) atomicAdd(&rangeA[b], cnt[b]);
}

// Exclusive scan of the 586 range totals, in place (1 block).
__global__ __launch_bounds__(1024) void scan_ranges(
    int* __restrict__ rangeA, int* __restrict__ rowPtr)
{
  __shared__ int wsum[16];
  const int tid  = threadIdx.x;
  const int lane = tid & 63;
  const int wid  = tid >> 6;
  const int cnt  = (tid < kNRanges) ? rangeA[tid] : 0;
  int v = cnt;
#pragma unroll
  for (int off = 1; off < 64; off <<= 1) {
    const int n = __shfl_up(v, off, 64);
    if (lane >= off) v += n;
  }
  if (lane == 63) wsum[wid] = v;
  __syncthreads();
  if (tid == 0) {
    int s = 0;
#pragma unroll
    for (int w = 0; w < 16; ++w) { const int t = wsum[w]; wsum[w] = s; s += t; }
  }
  __syncthreads();
  if (tid < kNRanges) rangeA[tid] = wsum[wid] + v - cnt;
  if (tid == 0) {
    rangeA[kNRanges]  = kNEdges;
    rowPtr[kNNodes]   = kNEdges;
  }
}

// Bin edges into 586 row-ranges. Per block: LDS histogram, ONE global atomic
// per (block,range) reserving a contiguous burst off rangeStart, then scatter
// into the exclusively-owned burst. Record: col | localRow<<18.
__global__ __launch_bounds__(1024) void bin_edges(
    const int* __restrict__ rows, const int* __restrict__ cols,
    const float* __restrict__ vals, const int* __restrict__ rangeA,
    int* __restrict__ rangeCnt, int2* __restrict__ tmpE)
{
  __shared__ int cnt[kNRanges];
  __shared__ int base[kNRanges];
  const int tid = threadIdx.x;
  const int e0  = blockIdx.x * kEdgesPerBin;
  int e1 = e0 + kEdgesPerBin;
  if (e1 > kNEdges) e1 = kNEdges;

  for (int b = tid; b < kNRanges; b += 1024) cnt[b] = 0;
  __syncthreads();
  for (int e = e0 + tid; e < e1; e += 1024)
    atomicAdd(&cnt[rows[e] >> kRngShift], 1);
  __syncthreads();
  for (int b = tid; b < kNRanges; b += 1024) {
    const int c = cnt[b];
    base[b] = (c > 0) ? (rangeA[b] + atomicAdd(&rangeCnt[b], c)) : 0;
    cnt[b] = 0;
  }
  __syncthreads();
  for (int e = e0 + tid; e < e1; e += 1024) {
    const int r = rows[e];
    const int b = r >> kRngShift;
    const int rank = atomicAdd(&cnt[b], 1);
    tmpE[base[b] + rank] =
        make_int2(cols[e] | ((r & 255) << 18), __float_as_int(vals[e]));
  }
}

// One WG per range: derive per-row CSR locally, SLICE-SORT each row's edges
// (3 col slices), write rowPtr + 2 sub-pointers per row, place edges.
__global__ __launch_bounds__(256) void place_edges(
    const int2* __restrict__ tmpE, const int* __restrict__ rangeA,
    int2* __restrict__ edgeS, int* __restrict__ rowPtr,
    int* __restrict__ rowPtrS)
{
  __shared__ int lcnt[256][4];    // per-(row,slice) counts then frontiers
  __shared__ int ws[4];
  const int b    = blockIdx.x;
  const int r0   = b << kRngShift;
  const int tid  = threadIdx.x;
  const int lane = tid & 63;
  const int wid  = tid >> 6;
  const int start = rangeA[b];
  const int end   = rangeA[b + 1];

  lcnt[tid][0] = 0; lcnt[tid][1] = 0; lcnt[tid][2] = 0;
  __syncthreads();
  for (int e = start + tid; e < end; e += 256) {
    const int cv  = tmpE[e].x;
    const int col = cv & 0x3FFFF;
    const int s   = (col >= kSlice2) ? 2 : ((col >= kSlice1) ? 1 : 0);
    atomicAdd(&lcnt[(cv >> 18) & 255][s], 1);
  }
  __syncthreads();

  const int c0 = lcnt[tid][0];
  const int c1 = lcnt[tid][1];
  const int c2 = lcnt[tid][2];
  const int c  = c0 + c1 + c2;
  int v = c;
#pragma unroll
  for (int off = 1; off < 64; off <<= 1) {
    const int n = __shfl_up(v, off, 64);
    if (lane >= off) v += n;
  }
  if (lane == 63) ws[wid] = v;
  __syncthreads();
  int wadd = 0;
#pragma unroll
  for (int w = 0; w < 4; ++w) if (w < wid) wadd += ws[w];
  const int rbase = start + v - c + wadd;   // absolute start of this row
  if (r0 + tid < kNNodes) {
    rowPtr[r0 + tid] = rbase;
    rowPtrS[r0 + tid]           = rbase + c0;       // slice-1 start
    rowPtrS[kNNodes + r0 + tid] = rbase + c0 + c1;  // slice-2 start
  }
  __syncthreads();          // lcnt reads done above; now reuse as frontiers
  lcnt[tid][0] = rbase;
  lcnt[tid][1] = rbase + c0;
  lcnt[tid][2] = rbase + c0 + c1;
  __syncthreads();

  for (int e = start + tid; e < end; e += 256) {
    const int2 cv = tmpE[e];
    const int rl  = (cv.x >> 18) & 255;
    const int col = cv.x & 0x3FFFF;
    const int s   = (col >= kSlice2) ? 2 : ((col >= kSlice1) ? 1 : 0);
    const int slot = atomicAdd(&lcnt[rl][s], 1);
    edgeS[slot] = make_int2(col, cv.y);
  }
}

// ---------------------------------------------------------------------------
// Slice-phased CSR SpMM pass, int8 gather: one wave per row, lane = dim.
// Within a pass, every gather targets one 3.2 MB slice -> XCD-L2 resident.
// accFlag: 0 = overwrite nbuf, 1 = accumulate into nbuf.
// ---------------------------------------------------------------------------
__global__ __launch_bounds__(256) void spmm_pass8(
    const signed char* __restrict__ cur8, const float* __restrict__ rowScale,
    const int* __restrict__ startPtr, const int* __restrict__ endPtr,
    const int2* __restrict__ edgeS, float* __restrict__ nbuf, int accFlag)
{
  const int lane = threadIdx.x & 63;
  const int r = (blockIdx.x << 2) | (threadIdx.x >> 6);
  if (r >= kNNodes) return;
  const int start = __builtin_amdgcn_readfirstlane(startPtr[r]);
  const int end   = __builtin_amdgcn_readfirstlane(endPtr[r]);
  float a0 = 0.f, a1 = 0.f, a2 = 0.f, a3 = 0.f;
  int e = start;
  for (; e + 4 <= end; e += 4) {
    const int2 cv0 = edgeS[e];
    const int2 cv1 = edgeS[e + 1];
    const int2 cv2 = edgeS[e + 2];
    const int2 cv3 = edgeS[e + 3];
    const int q0 = cur8[(size_t)cv0.x * EMB + lane];
    const int q1 = cur8[(size_t)cv1.x * EMB + lane];
    const int q2 = cur8[(size_t)cv2.x * EMB + lane];
    const int q3 = cur8[(size_t)cv3.x * EMB + lane];
    const float s0 = __int_as_float(cv0.y) * rowScale[cv0.x];
    const float s1 = __int_as_float(cv1.y) * rowScale[cv1.x];
    const float s2 = __int_as_float(cv2.y) * rowScale[cv2.x];
    const float s3 = __int_as_float(cv3.y) * rowScale[cv3.x];
    a0 = fmaf(s0, (float)q0, a0);
    a1 = fmaf(s1, (float)q1, a1);
    a2 = fmaf(s2, (float)q2, a2);
    a3 = fmaf(s3, (float)q3, a3);
  }
  for (; e < end; ++e) {
    const int2 cv = edgeS[e];
    const int q = cur8[(size_t)cv.x * EMB + lane];
    a0 = fmaf(__int_as_float(cv.y) * rowScale[cv.x], (float)q, a0);
  }
  float sum = (a0 + a1) + (a2 + a3);
  float* p = nbuf + (size_t)r * EMB + lane;
  if (accFlag) sum += *p;
  *p = sum;
}

// Tiny-workspace fallback: edge-parallel atomic SpMM on fp32.
__global__ __launch_bounds__(256) void spmm_atomic(
    const float* __restrict__ cur, const int* __restrict__ rows,
    const int* __restrict__ cols, const float* __restrict__ vals,
    float* __restrict__ nbuf)
{
  const int lane = threadIdx.x & 63;
  int wv = (blockIdx.x << 2) | (threadIdx.x >> 6);
  wv = __builtin_amdgcn_readfirstlane(wv);
  int e0 = wv * kEPW;
  int e1 = e0 + kEPW;
  if (e1 > kNEdges) e1 = kNEdges;
  for (int e = e0; e < e1; ++e) {
    atomicAdd(nbuf + (size_t)rows[e] * EMB + lane,
              vals[e] * cur[(size_t)cols[e] * EMB + lane]);
  }
}

// ---------------------------------------------------------------------------
// Transform pass 1: t = n@W2 + b2, in place over nbuf. Named-register accs.
// ---------------------------------------------------------------------------
__global__ __launch_bounds__(256) void transform_nbr(
    float* __restrict__ nbuf, const float* __restrict__ W2,
    const float* __restrict__ b2)
{
  const int node = blockIdx.x * 256 + threadIdx.x;
  if (node >= kNNodes) return;
  const float4* __restrict__ nr  = (const float4*)(nbuf + (size_t)node * EMB);
  const float4* __restrict__ b2v = (const float4*)b2;
#define DECL(j) float4 a##j = b2v[j];
  F16(DECL)
#undef DECL
#pragma unroll 4
  for (int k4 = 0; k4 < 16; ++k4) {
    const float4 nv = nr[k4];
#pragma unroll
    for (int kk = 0; kk < 4; ++kk) {
      const float ns = f4c(nv, kk);
      const float4* __restrict__ w2r = (const float4*)(W2 + (4 * k4 + kk) * EMB);
#define STEP(j) a##j = f4fma(ns, w2r[j], a##j);
      F16(STEP)
#undef STEP
    }
  }
  float4* __restrict__ outp = (float4*)(nbuf + (size_t)node * EMB);
#define STORE(j) outp[j] = a##j;
  F16(STORE)
#undef STORE
}

// ---------------------------------------------------------------------------
// Transform pass 2: cur = lrelu(x@W1 + b1 + b2 + (t*x)@W2 + t), t from nbuf.
// ---------------------------------------------------------------------------
__global__ __launch_bounds__(256) void transform_self(
    float* __restrict__ cur, const float* __restrict__ nbuf,
    const float* __restrict__ W1, const float* __restrict__ b1,
    const float* __restrict__ b2, const float* __restrict__ W2)
{
  const int node = blockIdx.x * 256 + threadIdx.x;
  if (node >= kNNodes) return;
  const float4* __restrict__ xr  = (const float4*)(cur  + (size_t)node * EMB);
  const float4* __restrict__ tr  = (const float4*)(nbuf + (size_t)node * EMB);
  const float4* __restrict__ b1v = (const float4*)b1;
  const float4* __restrict__ b2v = (const float4*)b2;
#define DECL(j) float4 a##j = f4add(b1v[j], b2v[j]);
  F16(DECL)
#undef DECL
#pragma unroll 2
  for (int k4 = 0; k4 < 16; ++k4) {
    const float4 xv = xr[k4];
    const float4 tv = tr[k4];
#pragma unroll
    for (int kk = 0; kk < 4; ++kk) {
      const float xs = f4c(xv, kk);
      const float ms = f4c(tv, kk) * xs;
      const int k = 4 * k4 + kk;
      const float4* __restrict__ w1r = (const float4*)(W1 + k * EMB);
      const float4* __restrict__ w2r = (const float4*)(W2 + k * EMB);
#define STEP(j) a##j = f4fma(xs, w1r[j], a##j); a##j = f4fma(ms, w2r[j], a##j);
      F16(STEP)
#undef STEP
    }
  }
  float4* __restrict__ outp = (float4*)(cur + (size_t)node * EMB);
#define STORE(j) { const float4 tj = tr[j]; float4 r;          \
    r.x = lrelu(a##j.x + tj.x); r.y = lrelu(a##j.y + tj.y);    \
    r.z = lrelu(a##j.z + tj.z); r.w = lrelu(a##j.w + tj.w);    \
    outp[j] = r; }
  F16(STORE)
#undef STORE
}

// ---------------------------------------------------------------------------
__global__ __launch_bounds__(256) void gather_out(
    const float* __restrict__ cur, const int* __restrict__ users,
    const int* __restrict__ pos, const int* __restrict__ neg,
    float* __restrict__ out, int layer)
{
  const int t    = blockIdx.x * 256 + threadIdx.x;
  const int lane = t & 63;
  const int rid  = t >> 6;
  if (rid >= 3 * kBatch) return;
  const int seg = rid / kBatch;
  const int b   = rid - seg * kBatch;
  int idx;
  if (seg == 0)      idx = users[b];
  else if (seg == 1) idx = pos[b] + kNUsers;
  else               idx = neg[b] + kNUsers;
  out[(size_t)rid * 256 + layer * EMB + lane] = cur[(size_t)idx * EMB + lane];
}

// ---------------------------------------------------------------------------
extern "C" void kernel_launch(void* const* d_in, const int* in_sizes, int n_in,
                              void* d_out, int out_size, void* d_ws, size_t ws_size,
                              hipStream_t stream) {
  const int*   users    = (const int*)d_in[0];
  const int*   pos      = (const int*)d_in[1];
  const int*   neg      = (const int*)d_in[2];
  const int*   rows     = (const int*)d_in[3];
  const int*   cols     = (const int*)d_in[4];
  const float* vals     = (const float*)d_in[5];
  const float* user_emb = (const float*)d_in[6];
  const float* item_emb = (const float*)d_in[7];
  const float* W1s      = (const float*)d_in[8];
  const float* b1s      = (const float*)d_in[9];
  const float* W2s      = (const float*)d_in[10];
  const float* b2s      = (const float*)d_in[11];
  float* out = (float*)d_out;

  const size_t nodeF = (size_t)kNNodes * EMB;
  float* cur  = (float*)d_ws;                               // 38.4 MB
  float* nbuf = cur + nodeF;                                // 38.4 MB (tmpE alias)
  int2*  edgeS     = (int2*)(nbuf + nodeF);                 // 38.4 MB
  int*   rowPtr    = (int*)(edgeS + kNEdges);               // 600 KB (+1)
  int*   rangeA    = rowPtr + (kNNodes + 1);                // 2.3 KB (+1)
  int*   rangeCnt  = rangeA + (kNRanges + 1);               // 2.3 KB
  int*   rowPtrS   = rangeCnt + kNRanges;                   // 1.2 MB (2x rows)
  signed char* cur8 = (signed char*)(rowPtrS + 2 * kNNodes);// 9.6 MB
  float* rowScale  = (float*)(cur8 + nodeF);                // 600 KB
  int2*  tmpE = (int2*)nbuf;                                // binned records
  const size_t needed = (size_t)((char*)(rowScale + kNNodes) - (char*)d_ws);
  const bool useCsr = ws_size >= needed;

  const dim3 blk(256);
  const int iblocks = (int)((nodeF / 4 + 255) / 256);       // 9375
  const int gblocks = (3 * kBatch * EMB + 255) / 256;       // 12288
  const int rblocks = (kNNodes + 3) / 4;                    // 37500
  const int tblocks = (kNNodes + 255) / 256;                // 586

  init_embed<<<iblocks, blk, 0, stream>>>(user_emb, item_emb, cur);

  if (useCsr) {
    quant8<<<rblocks, blk, 0, stream>>>(cur, cur8, rowScale);
    // zero rangeA (totals) + rangeCnt (burst frontiers) — contiguous
    hipMemsetAsync(rangeA, 0, (size_t)(2 * kNRanges + 1) * sizeof(int), stream);
    hist_ranges<<<kBinBlocks, dim3(1024), 0, stream>>>(rows, rangeA);
    scan_ranges<<<1, 1024, 0, stream>>>(rangeA, rowPtr);
    bin_edges<<<kBinBlocks, dim3(1024), 0, stream>>>(rows, cols, vals, rangeA,
                                                     rangeCnt, tmpE);
    place_edges<<<kNRanges, blk, 0, stream>>>(tmpE, rangeA, edgeS, rowPtr,
                                              rowPtrS);
  }

  gather_out<<<gblocks, blk, 0, stream>>>(cur, users, pos, neg, out, 0);

  for (int L = 0; L < kLayers; ++L) {
    if (useCsr) {
      // slice 0: [rowPtr, rowPtrS0)   — cols [0, 50000)
      spmm_pass8<<<rblocks, blk, 0, stream>>>(cur8, rowScale, rowPtr, rowPtrS,
                                              edgeS, nbuf, 0);
      // slice 1: [rowPtrS0, rowPtrS1) — cols [50000, 100000)
      spmm_pass8<<<rblocks, blk, 0, stream>>>(cur8, rowScale, rowPtrS,
                                              rowPtrS + kNNodes, edgeS, nbuf, 1);
      // slice 2: [rowPtrS1, rowPtr+1) — cols [100000, 150000)
      spmm_pass8<<<rblocks, blk, 0, stream>>>(cur8, rowScale, rowPtrS + kNNodes,
                                              rowPtr + 1, edgeS, nbuf, 1);
    } else {
      hipMemsetAsync(nbuf, 0, nodeF * sizeof(float), stream);
      const int sblocks = (((kNEdges + kEPW - 1) / kEPW) + 3) / 4;
      spmm_atomic<<<sblocks, blk, 0, stream>>>(cur, rows, cols, vals, nbuf);
    }
    transform_nbr<<<tblocks, blk, 0, stream>>>(
        nbuf, W2s + L * EMB * EMB, b2s + L * EMB);
    transform_self<<<tblocks, blk, 0, stream>>>(
        cur, nbuf, W1s + L * EMB * EMB, b1s + L * EMB,
        b2s + L * EMB, W2s + L * EMB * EMB);
    if (useCsr && L + 1 < kLayers)
      quant8<<<rblocks, blk, 0, stream>>>(cur, cur8, rowScale);
    gather_out<<<gblocks, blk, 0, stream>>>(cur, users, pos, neg, out, L + 1);
  }
}

// Round 9
// 1177.047 us; speedup vs baseline: 1.2545x; 1.2545x over previous
//
#include <hip/hip_runtime.h>

// NGCF forward on gfx950 — round 15: revert to best-known (R12 config, bf16
// single-pass spmm) + fuse transform_nbr into the spmm epilogue.
// R13/R14 post-mortem: random-gather spmm sits on a ~4 TB/s miss-granule
// ceiling at ~15-17% L2 hit for ANY edge order (R12 bucket null, R14 slice
// passes regressed on RMW+launch overhead). 147 us bf16 spmm = its roofline.
// Fusion: after the edge loop the wave holds n[lane]; t = b2 + n@W2 via 64
// compile-time shuffles (v_readlane->SGPR) + 64 FMA against L1-hot W2 (16 KB),
// hidden under gather stalls (VALUBusy 17%). transform_nbr (77 MB x3) deleted.

#define EMB 64

constexpr int kNUsers = 100000;
constexpr int kNItems = 50000;
constexpr int kNNodes = 150000;
constexpr int kNEdges = 4800000;
constexpr int kBatch  = 16384;
constexpr int kLayers = 3;
constexpr int kRngShift = 8;                     // 256 rows per range
constexpr int kNRanges  = (kNNodes + 255) >> 8;  // 586
constexpr int kEdgesPerBin = 16384;              // edges per bin block
constexpr int kBinBlocks = (kNEdges + kEdgesPerBin - 1) / kEdgesPerBin; // 293
constexpr int kEPW    = 16;                      // fallback only

__device__ __forceinline__ float f4c(const float4& v, int i) {
  return ((const float*)&v)[i];
}
__device__ __forceinline__ float4 f4fma(float s, float4 w, float4 a) {
  a.x = fmaf(s, w.x, a.x);
  a.y = fmaf(s, w.y, a.y);
  a.z = fmaf(s, w.z, a.z);
  a.w = fmaf(s, w.w, a.w);
  return a;
}
__device__ __forceinline__ float4 f4add(float4 a, float4 b) {
  a.x += b.x; a.y += b.y; a.z += b.z; a.w += b.w;
  return a;
}
__device__ __forceinline__ float lrelu(float x) { return x > 0.f ? x : 0.2f * x; }
__device__ __forceinline__ unsigned short f2bf(float f) {   // RNE
  unsigned int u = __float_as_uint(f);
  u = (u + 0x7fffu + ((u >> 16) & 1u)) >> 16;
  return (unsigned short)u;
}
__device__ __forceinline__ float bf2f(unsigned short h) {
  return __uint_as_float(((unsigned int)h) << 16);
}

#define F16(M) M(0) M(1) M(2) M(3) M(4) M(5) M(6) M(7) \
               M(8) M(9) M(10) M(11) M(12) M(13) M(14) M(15)

// ---------------------------------------------------------------------------
// init: cur = concat(user_emb, item_emb); cur16 = bf16(cur).
// ---------------------------------------------------------------------------
__global__ __launch_bounds__(256) void init_embed(
    const float* __restrict__ user_emb, const float* __restrict__ item_emb,
    float* __restrict__ cur, unsigned short* __restrict__ cur16, int with16)
{
  const size_t userF = (size_t)kNUsers * EMB;
  const size_t allF4 = (size_t)kNNodes * EMB / 4;
  const size_t i = (size_t)blockIdx.x * 256 + threadIdx.x;
  if (i >= allF4) return;
  const size_t f = i * 4;
  const float4 v = (f < userF) ? ((const float4*)user_emb)[i]
                               : ((const float4*)(item_emb))[(f - userF) / 4];
  ((float4*)cur)[i] = v;
  if (with16) {
    ushort4 h;
    h.x = f2bf(v.x); h.y = f2bf(v.y); h.z = f2bf(v.z); h.w = f2bf(v.w);
    ((ushort4*)cur16)[i] = h;
  }
}

// Streaming bf16 shadow refresh: cur16 = bf16(cur).
__global__ __launch_bounds__(256) void refresh16(
    const float* __restrict__ cur, unsigned short* __restrict__ cur16)
{
  const size_t allF4 = (size_t)kNNodes * EMB / 4;
  const size_t i = (size_t)blockIdx.x * 256 + threadIdx.x;
  if (i >= allF4) return;
  const float4 v = ((const float4*)cur)[i];
  ushort4 h;
  h.x = f2bf(v.x); h.y = f2bf(v.y); h.z = f2bf(v.z); h.w = f2bf(v.w);
  ((ushort4*)cur16)[i] = h;
}

// ---------------------------------------------------------------------------
// CSR build: range histogram -> range scan -> burst binning -> local place.
// ---------------------------------------------------------------------------

// Per-block LDS histogram over 586 ranges; one global atomic per (block,range).
__global__ __launch_bounds__(1024) void hist_ranges(
    const int* __restrict__ rows, int* __restrict__ rangeA)
{
  __shared__ int cnt[kNRanges];
  const int tid = threadIdx.x;
  const int e0  = blockIdx.x * kEdgesPerBin;
  int e1 = e0 + kEdgesPerBin;
  if (e1 > kNEdges) e1 = kNEdges;
  for (int b = tid; b < kNRanges; b += 1024) cnt[b] = 0;
  __syncthreads();
  for (int e = e0 + tid; e < e1; e += 1024)
    atomicAdd(&cnt[rows[e] >> kRngShift], 1);
  __syncthreads();
  for (int b = tid; b < kNRanges; b += 1024)
    if (cnt[b] > 0) atomicAdd(&rangeA[b], cnt[b]);
}

// Exclusive scan of the 586 range totals, in place (1 block).
__global__ __launch_bounds__(1024) void scan_ranges(
    int* __restrict__ rangeA, int* __restrict__ rowPtr)
{
  __shared__ int wsum[16];
  const int tid  = threadIdx.x;
  const int lane = tid & 63;
  const int wid  = tid >> 6;
  const int cnt  = (tid < kNRanges) ? rangeA[tid] : 0;
  int v = cnt;
#pragma unroll
  for (int off = 1; off < 64; off <<= 1) {
    const int n = __shfl_up(v, off, 64);
    if (lane >= off) v += n;
  }
  if (lane == 63) wsum[wid] = v;
  __syncthreads();
  if (tid == 0) {
    int s = 0;
#pragma unroll
    for (int w = 0; w < 16; ++w) { const int t = wsum[w]; wsum[w] = s; s += t; }
  }
  __syncthreads();
  if (tid < kNRanges) rangeA[tid] = wsum[wid] + v - cnt;
  if (tid == 0) {
    rangeA[kNRanges]  = kNEdges;
    rowPtr[kNNodes]   = kNEdges;
  }
}

// Bin edges into 586 row-ranges. Per block: LDS histogram, ONE global atomic
// per (block,range) reserving a contiguous burst off rangeStart, then scatter
// into the exclusively-owned burst. Record: col | localRow<<18.
__global__ __launch_bounds__(1024) void bin_edges(
    const int* __restrict__ rows, const int* __restrict__ cols,
    const float* __restrict__ vals, const int* __restrict__ rangeA,
    int* __restrict__ rangeCnt, int2* __restrict__ tmpE)
{
  __shared__ int cnt[kNRanges];
  __shared__ int base[kNRanges];
  const int tid = threadIdx.x;
  const int e0  = blockIdx.x * kEdgesPerBin;
  int e1 = e0 + kEdgesPerBin;
  if (e1 > kNEdges) e1 = kNEdges;

  for (int b = tid; b < kNRanges; b += 1024) cnt[b] = 0;
  __syncthreads();
  for (int e = e0 + tid; e < e1; e += 1024)
    atomicAdd(&cnt[rows[e] >> kRngShift], 1);
  __syncthreads();
  for (int b = tid; b < kNRanges; b += 1024) {
    const int c = cnt[b];
    base[b] = (c > 0) ? (rangeA[b] + atomicAdd(&rangeCnt[b], c)) : 0;
    cnt[b] = 0;
  }
  __syncthreads();
  for (int e = e0 + tid; e < e1; e += 1024) {
    const int r = rows[e];
    const int b = r >> kRngShift;
    const int rank = atomicAdd(&cnt[b], 1);
    tmpE[base[b] + rank] =
        make_int2(cols[e] | ((r & 255) << 18), __float_as_int(vals[e]));
  }
}

// One WG per range: derive local per-row CSR (LDS hist + block scan over the
// L2-resident slab), write rowPtr for its 256 rows, then place each edge at
// its exact CSR slot.
__global__ __launch_bounds__(256) void place_edges(
    const int2* __restrict__ tmpE, const int* __restrict__ rangeA,
    int2* __restrict__ edgeS, int* __restrict__ rowPtr)
{
  __shared__ int lcnt[256];
  __shared__ int lbase[256];
  __shared__ int ws[4];
  const int b    = blockIdx.x;
  const int r0   = b << kRngShift;
  const int tid  = threadIdx.x;
  const int lane = tid & 63;
  const int wid  = tid >> 6;
  const int start = rangeA[b];
  const int end   = rangeA[b + 1];

  lcnt[tid] = 0;
  __syncthreads();
  for (int e = start + tid; e < end; e += 256)
    atomicAdd(&lcnt[(tmpE[e].x >> 18) & 255], 1);
  __syncthreads();

  const int c = lcnt[tid];
  int v = c;
#pragma unroll
  for (int off = 1; off < 64; off <<= 1) {
    const int n = __shfl_up(v, off, 64);
    if (lane >= off) v += n;
  }
  if (lane == 63) ws[wid] = v;
  __syncthreads();
  int wadd = 0;
#pragma unroll
  for (int w = 0; w < 4; ++w) if (w < wid) wadd += ws[w];
  const int excl = v - c + wadd;
  lbase[tid] = start + excl;
  if (r0 + tid < kNNodes) rowPtr[r0 + tid] = start + excl;
  lcnt[tid] = 0;
  __syncthreads();

  for (int e = start + tid; e < end; e += 256) {
    const int2 cv = tmpE[e];
    const int rl  = (cv.x >> 18) & 255;
    const int rank = atomicAdd(&lcnt[rl], 1);
    edgeS[lbase[rl] + rank] = make_int2(cv.x & 0x3FFFF, cv.y);
  }
}

// ---------------------------------------------------------------------------
// CSR SpMM, bf16 gather, FUSED with t = n@W2 + b2.
// One wave per row, lane = dim. Edge loop unchanged (147 us roofline); the
// epilogue does 64 compile-time readlane broadcasts + FMA vs L1-hot W2 and
// writes t (not n) to nbuf — transform_nbr kernel eliminated.
// ---------------------------------------------------------------------------
__global__ __launch_bounds__(256) void spmm_csr16f(
    const unsigned short* __restrict__ cur16, const int* __restrict__ rowPtr,
    const int2* __restrict__ edgeS, const float* __restrict__ W2,
    const float* __restrict__ b2, float* __restrict__ nbuf)
{
  const int lane = threadIdx.x & 63;
  const int r = (blockIdx.x << 2) | (threadIdx.x >> 6);
  if (r >= kNNodes) return;
  const int start = __builtin_amdgcn_readfirstlane(rowPtr[r]);
  const int end   = __builtin_amdgcn_readfirstlane(rowPtr[r + 1]);
  float a0 = 0.f, a1 = 0.f, a2 = 0.f, a3 = 0.f;
  int e = start;
  for (; e + 4 <= end; e += 4) {
    const int2 cv0 = edgeS[e];
    const int2 cv1 = edgeS[e + 1];
    const int2 cv2 = edgeS[e + 2];
    const int2 cv3 = edgeS[e + 3];
    const unsigned short u0 = cur16[(size_t)cv0.x * EMB + lane];
    const unsigned short u1 = cur16[(size_t)cv1.x * EMB + lane];
    const unsigned short u2 = cur16[(size_t)cv2.x * EMB + lane];
    const unsigned short u3 = cur16[(size_t)cv3.x * EMB + lane];
    a0 = fmaf(__int_as_float(cv0.y), bf2f(u0), a0);
    a1 = fmaf(__int_as_float(cv1.y), bf2f(u1), a1);
    a2 = fmaf(__int_as_float(cv2.y), bf2f(u2), a2);
    a3 = fmaf(__int_as_float(cv3.y), bf2f(u3), a3);
  }
  for (; e < end; ++e) {
    const int2 cv = edgeS[e];
    a0 = fmaf(__int_as_float(cv.y), bf2f(cur16[(size_t)cv.x * EMB + lane]), a0);
  }
  const float nsum = (a0 + a1) + (a2 + a3);

  // t[lane] = b2[lane] + sum_k n[k] * W2[k][lane]
  float t = b2[lane];
#pragma unroll
  for (int k = 0; k < 64; ++k) {
    const float nk = __shfl(nsum, k, 64);   // compile-time k -> v_readlane
    t = fmaf(nk, W2[k * EMB + lane], t);
  }
  nbuf[(size_t)r * EMB + lane] = t;
}

// fp32-gather variant (fallback when ws can't hold cur16) — unfused.
__global__ __launch_bounds__(256) void spmm_csr(
    const float* __restrict__ cur, const int* __restrict__ rowPtr,
    const int2* __restrict__ edgeS, float* __restrict__ nbuf)
{
  const int lane = threadIdx.x & 63;
  const int r = (blockIdx.x << 2) | (threadIdx.x >> 6);
  if (r >= kNNodes) return;
  const int start = __builtin_amdgcn_readfirstlane(rowPtr[r]);
  const int end   = __builtin_amdgcn_readfirstlane(rowPtr[r + 1]);
  float a0 = 0.f, a1 = 0.f, a2 = 0.f, a3 = 0.f;
  int e = start;
  for (; e + 4 <= end; e += 4) {
    const int2 cv0 = edgeS[e];
    const int2 cv1 = edgeS[e + 1];
    const int2 cv2 = edgeS[e + 2];
    const int2 cv3 = edgeS[e + 3];
    a0 = fmaf(__int_as_float(cv0.y), cur[(size_t)cv0.x * EMB + lane], a0);
    a1 = fmaf(__int_as_float(cv1.y), cur[(size_t)cv1.x * EMB + lane], a1);
    a2 = fmaf(__int_as_float(cv2.y), cur[(size_t)cv2.x * EMB + lane], a2);
    a3 = fmaf(__int_as_float(cv3.y), cur[(size_t)cv3.x * EMB + lane], a3);
  }
  for (; e < end; ++e) {
    const int2 cv = edgeS[e];
    a0 = fmaf(__int_as_float(cv.y), cur[(size_t)cv.x * EMB + lane], a0);
  }
  nbuf[(size_t)r * EMB + lane] = (a0 + a1) + (a2 + a3);
}

__global__ __launch_bounds__(256) void spmm_atomic(
    const float* __restrict__ cur, const int* __restrict__ rows,
    const int* __restrict__ cols, const float* __restrict__ vals,
    float* __restrict__ nbuf)
{
  const int lane = threadIdx.x & 63;
  int wv = (blockIdx.x << 2) | (threadIdx.x >> 6);
  wv = __builtin_amdgcn_readfirstlane(wv);
  int e0 = wv * kEPW;
  int e1 = e0 + kEPW;
  if (e1 > kNEdges) e1 = kNEdges;
  for (int e = e0; e < e1; ++e) {
    atomicAdd(nbuf + (size_t)rows[e] * EMB + lane,
              vals[e] * cur[(size_t)cols[e] * EMB + lane]);
  }
}

// ---------------------------------------------------------------------------
// Fallback-only: t = n@W2 + b2, in place over nbuf (for the non-CSR path).
// ---------------------------------------------------------------------------
__global__ __launch_bounds__(256) void transform_nbr(
    float* __restrict__ nbuf, const float* __restrict__ W2,
    const float* __restrict__ b2)
{
  const int node = blockIdx.x * 256 + threadIdx.x;
  if (node >= kNNodes) return;
  const float4* __restrict__ nr  = (const float4*)(nbuf + (size_t)node * EMB);
  const float4* __restrict__ b2v = (const float4*)b2;
#define DECL(j) float4 a##j = b2v[j];
  F16(DECL)
#undef DECL
#pragma unroll 4
  for (int k4 = 0; k4 < 16; ++k4) {
    const float4 nv = nr[k4];
#pragma unroll
    for (int kk = 0; kk < 4; ++kk) {
      const float ns = f4c(nv, kk);
      const float4* __restrict__ w2r = (const float4*)(W2 + (4 * k4 + kk) * EMB);
#define STEP(j) a##j = f4fma(ns, w2r[j], a##j);
      F16(STEP)
#undef STEP
    }
  }
  float4* __restrict__ outp = (float4*)(nbuf + (size_t)node * EMB);
#define STORE(j) outp[j] = a##j;
  F16(STORE)
#undef STORE
}

// ---------------------------------------------------------------------------
// Transform pass 2: cur = lrelu(x@W1 + b1 + b2 + (t*x)@W2 + t), t from nbuf.
// ---------------------------------------------------------------------------
__global__ __launch_bounds__(256) void transform_self(
    float* __restrict__ cur, const float* __restrict__ nbuf,
    const float* __restrict__ W1, const float* __restrict__ b1,
    const float* __restrict__ b2, const float* __restrict__ W2)
{
  const int node = blockIdx.x * 256 + threadIdx.x;
  if (node >= kNNodes) return;
  const float4* __restrict__ xr  = (const float4*)(cur  + (size_t)node * EMB);
  const float4* __restrict__ tr  = (const float4*)(nbuf + (size_t)node * EMB);
  const float4* __restrict__ b1v = (const float4*)b1;
  const float4* __restrict__ b2v = (const float4*)b2;
#define DECL(j) float4 a##j = f4add(b1v[j], b2v[j]);
  F16(DECL)
#undef DECL
#pragma unroll 2
  for (int k4 = 0; k4 < 16; ++k4) {
    const float4 xv = xr[k4];
    const float4 tv = tr[k4];
#pragma unroll
    for (int kk = 0; kk < 4; ++kk) {
      const float xs = f4c(xv, kk);
      const float ms = f4c(tv, kk) * xs;
      const int k = 4 * k4 + kk;
      const float4* __restrict__ w1r = (const float4*)(W1 + k * EMB);
      const float4* __restrict__ w2r = (const float4*)(W2 + k * EMB);
#define STEP(j) a##j = f4fma(xs, w1r[j], a##j); a##j = f4fma(ms, w2r[j], a##j);
      F16(STEP)
#undef STEP
    }
  }
  float4* __restrict__ outp = (float4*)(cur + (size_t)node * EMB);
#define STORE(j) { const float4 tj = tr[j]; float4 r;          \
    r.x = lrelu(a##j.x + tj.x); r.y = lrelu(a##j.y + tj.y);    \
    r.z = lrelu(a##j.z + tj.z); r.w = lrelu(a##j.w + tj.w);    \
    outp[j] = r; }
  F16(STORE)
#undef STORE
}

// ---------------------------------------------------------------------------
__global__ __launch_bounds__(256) void gather_out(
    const float* __restrict__ cur, const int* __restrict__ users,
    const int* __restrict__ pos, const int* __restrict__ neg,
    float* __restrict__ out, int layer)
{
  const int t    = blockIdx.x * 256 + threadIdx.x;
  const int lane = t & 63;
  const int rid  = t >> 6;
  if (rid >= 3 * kBatch) return;
  const int seg = rid / kBatch;
  const int b   = rid - seg * kBatch;
  int idx;
  if (seg == 0)      idx = users[b];
  else if (seg == 1) idx = pos[b] + kNUsers;
  else               idx = neg[b] + kNUsers;
  out[(size_t)rid * 256 + layer * EMB + lane] = cur[(size_t)idx * EMB + lane];
}

// ---------------------------------------------------------------------------
extern "C" void kernel_launch(void* const* d_in, const int* in_sizes, int n_in,
                              void* d_out, int out_size, void* d_ws, size_t ws_size,
                              hipStream_t stream) {
  const int*   users    = (const int*)d_in[0];
  const int*   pos      = (const int*)d_in[1];
  const int*   neg      = (const int*)d_in[2];
  const int*   rows     = (const int*)d_in[3];
  const int*   cols     = (const int*)d_in[4];
  const float* vals     = (const float*)d_in[5];
  const float* user_emb = (const float*)d_in[6];
  const float* item_emb = (const float*)d_in[7];
  const float* W1s      = (const float*)d_in[8];
  const float* b1s      = (const float*)d_in[9];
  const float* W2s      = (const float*)d_in[10];
  const float* b2s      = (const float*)d_in[11];
  float* out = (float*)d_out;

  const size_t nodeF = (size_t)kNNodes * EMB;
  float* cur  = (float*)d_ws;                               // 38.4 MB
  float* nbuf = cur + nodeF;                                // 38.4 MB (tmpE alias)
  int2*  edgeS     = (int2*)(nbuf + nodeF);                 // 38.4 MB
  int*   rowPtr    = (int*)(edgeS + kNEdges);               // 600 KB (+1)
  int*   rangeA    = rowPtr + (kNNodes + 1);                // 2.3 KB (+1)
  int*   rangeCnt  = rangeA + (kNRanges + 1);               // 2.3 KB
  unsigned short* cur16 = (unsigned short*)(rangeCnt + kNRanges);  // 19.2 MB
  int2*  tmpE = (int2*)nbuf;                                // binned records
  const size_t neededCsr = (size_t)((char*)cur16 - (char*)d_ws);
  const size_t needed16  = neededCsr + nodeF * sizeof(unsigned short);
  const bool useCsr = ws_size >= neededCsr;
  const bool use16  = useCsr && ws_size >= needed16;

  const dim3 blk(256);
  const int iblocks = (int)((nodeF / 4 + 255) / 256);       // 9375
  const int gblocks = (3 * kBatch * EMB + 255) / 256;       // 12288
  const int rblocks = (kNNodes + 3) / 4;                    // 37500
  const int tblocks = (kNNodes + 255) / 256;                // 586

  init_embed<<<iblocks, blk, 0, stream>>>(user_emb, item_emb, cur, cur16,
                                          use16 ? 1 : 0);

  if (useCsr) {
    // zero rangeA (totals) + rangeCnt (burst frontiers) — contiguous
    hipMemsetAsync(rangeA, 0, (size_t)(2 * kNRanges + 1) * sizeof(int), stream);
    hist_ranges<<<kBinBlocks, dim3(1024), 0, stream>>>(rows, rangeA);
    scan_ranges<<<1, 1024, 0, stream>>>(rangeA, rowPtr);
    bin_edges<<<kBinBlocks, dim3(1024), 0, stream>>>(rows, cols, vals, rangeA,
                                                     rangeCnt, tmpE);
    place_edges<<<kNRanges, blk, 0, stream>>>(tmpE, rangeA, edgeS, rowPtr);
  }

  gather_out<<<gblocks, blk, 0, stream>>>(cur, users, pos, neg, out, 0);

  for (int L = 0; L < kLayers; ++L) {
    const float* W1 = W1s + L * EMB * EMB;
    const float* b1 = b1s + L * EMB;
    const float* W2 = W2s + L * EMB * EMB;
    const float* b2 = b2s + L * EMB;
    if (useCsr && use16) {
      // fused: nbuf <- t = (A @ cur) @ W2 + b2
      spmm_csr16f<<<rblocks, blk, 0, stream>>>(cur16, rowPtr, edgeS, W2, b2,
                                               nbuf);
    } else if (useCsr) {
      spmm_csr<<<rblocks, blk, 0, stream>>>(cur, rowPtr, edgeS, nbuf);
      transform_nbr<<<tblocks, blk, 0, stream>>>(nbuf, W2, b2);
    } else {
      hipMemsetAsync(nbuf, 0, nodeF * sizeof(float), stream);
      const int sblocks = (((kNEdges + kEPW - 1) / kEPW) + 3) / 4;
      spmm_atomic<<<sblocks, blk, 0, stream>>>(cur, rows, cols, vals, nbuf);
      transform_nbr<<<tblocks, blk, 0, stream>>>(nbuf, W2, b2);
    }
    transform_self<<<tblocks, blk, 0, stream>>>(cur, nbuf, W1, b1, b2, W2);
    if (use16 && L + 1 < kLayers)
      refresh16<<<iblocks, blk, 0, stream>>>(cur, cur16);
    gather_out<<<gblocks, blk, 0, stream>>>(cur, users, pos, neg, out, L + 1);
  }
}